// Round 8
// baseline (218.535 us; speedup 1.0000x reference)
//
#include <hip/hip_runtime.h>

// NTK-SVGP forward: D=H=128, C=10, N=256, M=128, T=128, sigma2=1, delta=1
#define H 128
#define DD 128
#define CC 10
#define NX 256
#define MZ 128
#define TN 128
#define S_TOT 512   // samples: X[0..255], Z[256..383], X_test[384..511]
#define SCALE (1.0f/256.0f)   // 1/(delta*N)
#define JIT 1e-3f
#define INV_S2 1.0f

// ---------------- ws layout (float offsets) ----------------
#define OFF_XS    0u
#define OFF_A1    (OFF_XS   + S_TOT*DD)
#define OFF_A2    (OFF_A1   + S_TOT*H)
#define OFF_G1    (OFF_A2   + S_TOT*H)
#define OFF_G2    (OFF_G1   + S_TOT*CC*H)
#define OFF_W2T   (OFF_G2   + S_TOT*CC*H)
#define OFF_BASE  (OFF_W2T  + H*H)
#define BASE_ZX   0u
#define BASE_ZZ   (3u*MZ*NX)
#define BASE_TZ   (3u*MZ*NX + 3u*MZ*MZ)
#define OFF_KZX   (OFF_BASE + 3u*MZ*NX + 3u*MZ*MZ + 3u*TN*MZ)
#define OFF_KZZ   (OFF_KZX  + CC*MZ*NX)
#define OFF_KXZ   (OFF_KZZ  + CC*MZ*MZ)
#define OFF_KXXD  (OFF_KXZ  + CC*TN*MZ)
#define OFF_KZZJ  (OFF_KXXD + CC*TN)
#define OFF_KZZB  (OFF_KZZJ + CC*MZ*MZ)
#define OFF_LAMU  (OFF_KZZB + CC*MZ*MZ)
#define OFF_LPAN  (OFF_LAMU + CC*MZ)
#define OFF_INVD  (OFF_LPAN + 2u*CC*MZ*MZ)
#define OFF_YLAM  (OFF_INVD + 2u*CC*MZ)
#define OFF_SSQ   (OFF_YLAM + CC*MZ)
#define OFF_FMEAN (OFF_SSQ  + 2u*CC*TN)

__global__ __launch_bounds__(128) void k_w2t(const float* __restrict__ W2, float* __restrict__ W2T,
                                             float* __restrict__ LamU) {
  int k = blockIdx.x, h = threadIdx.x;
  W2T[k*H + h] = W2[h*H + k];
  if (k < CC) LamU[k*MZ + h] = 0.0f;   // zero for k_gram's atomic accumulation
}

// Per-sample forward + backprop features. One block per sample, 128 threads.
__global__ __launch_bounds__(128) void k_features(
    const float* __restrict__ X, const float* __restrict__ Z, const float* __restrict__ Xt,
    const float* __restrict__ W1, const float* __restrict__ b1,
    const float* __restrict__ W2, const float* __restrict__ b2,
    const float* __restrict__ W3, const float* __restrict__ W2T,
    float* __restrict__ XS, float* __restrict__ A1, float* __restrict__ A2,
    float* __restrict__ G1, float* __restrict__ G2)
{
  int s = blockIdx.x, h = threadIdx.x;
  const float* xin = (s < NX) ? X + s*DD : (s < NX+MZ ? Z + (s-NX)*DD : Xt + (s-NX-MZ)*DD);
  __shared__ float xs[DD], a1s[H], g2s[CC*H];
  float xv = xin[h];
  xs[h] = xv; XS[s*DD + h] = xv;
  __syncthreads();
  float acc = b1[h];
  #pragma unroll 4
  for (int d0 = 0; d0 < DD; ++d0) acc += xs[d0] * W1[d0*H + h];   // coalesced over h
  float a1 = tanhf(acc);
  a1s[h] = a1; A1[s*H + h] = a1;
  __syncthreads();
  acc = b2[h];
  #pragma unroll 4
  for (int d0 = 0; d0 < H; ++d0) acc += a1s[d0] * W2[d0*H + h];
  float a2 = tanhf(acc);
  A2[s*H + h] = a2;
  float t2 = 1.0f - a2*a2;
  #pragma unroll
  for (int c = 0; c < CC; ++c) {
    float g2 = W3[h*CC + c] * t2;
    g2s[c*H + h] = g2;
    G2[(s*CC + c)*H + h] = g2;
  }
  __syncthreads();
  float t1 = 1.0f - a1*a1;
  float accs[CC];
  #pragma unroll
  for (int c = 0; c < CC; ++c) accs[c] = 0.0f;
  for (int k = 0; k < H; ++k) {
    float w = W2T[k*H + h];        // coalesced over h
    #pragma unroll
    for (int c = 0; c < CC; ++c) accs[c] += w * g2s[c*H + k];   // broadcast
  }
  #pragma unroll
  for (int c = 0; c < CC; ++c) G1[(s*CC + c)*H + h] = t1 * accs[c];
}

// Class-independent base dot products: 1+x.x', 1+a1.a1', 1+a2.a2'
__global__ __launch_bounds__(256) void k_base(const float* __restrict__ XS,
    const float* __restrict__ A1, const float* __restrict__ A2, float* __restrict__ Base)
{
  int set = blockIdx.z;
  int colsN = (set == 0) ? NX : MZ;
  if ((int)blockIdx.x * 16 >= colsN) return;
  int rowOff = (set == 2) ? NX+MZ : NX;
  int colOff = (set == 0) ? 0 : NX;
  unsigned baseOff = (set == 0) ? BASE_ZX : (set == 1 ? BASE_ZZ : BASE_TZ);
  __shared__ float rx[16*132], r1[16*132], r2[16*132], cxs[16*132], c1s[16*132], c2s[16*132];
  int tid = threadIdx.x, m0 = blockIdx.y*16, n0 = blockIdx.x*16;
  for (int idx = tid; idx < 16*128; idx += 256) {
    int r = idx >> 7, hh = idx & 127;
    int sr = rowOff + m0 + r, sc = colOff + n0 + r;
    rx [r*132+hh] = XS[sr*DD+hh]; r1[r*132+hh] = A1[sr*H+hh]; r2[r*132+hh] = A2[sr*H+hh];
    cxs[r*132+hh] = XS[sc*DD+hh]; c1s[r*132+hh] = A1[sc*H+hh]; c2s[r*132+hh] = A2[sc*H+hh];
  }
  __syncthreads();
  int ty = tid >> 4, tx = tid & 15;
  const float4* pa = (const float4*)(rx  + ty*132);
  const float4* pb = (const float4*)(cxs + tx*132);
  const float4* pc = (const float4*)(r1  + ty*132);
  const float4* pd = (const float4*)(c1s + tx*132);
  const float4* pe = (const float4*)(r2  + ty*132);
  const float4* pf = (const float4*)(c2s + tx*132);
  float d0 = 0, d1 = 0, d2 = 0;
  #pragma unroll 8
  for (int q = 0; q < 32; ++q) {
    float4 a = pa[q], b = pb[q]; d0 += a.x*b.x + a.y*b.y + a.z*b.z + a.w*b.w;
    float4 c = pc[q], d = pd[q]; d1 += c.x*d.x + c.y*d.y + c.z*d.z + c.w*d.w;
    float4 e = pe[q], f = pf[q]; d2 += e.x*f.x + e.y*f.y + e.z*f.z + e.w*f.w;
  }
  int m = m0 + ty, n = n0 + tx;
  float* Bp = Base + baseOff;
  int area = 128 * colsN;
  Bp[0*area + m*colsN + n] = 1.0f + d0;
  Bp[1*area + m*colsN + n] = 1.0f + d1;
  Bp[2*area + m*colsN + n] = 1.0f + d2;
}

// Per-class NTK gram: K = SCALE*(B0*(g1.g1') + B1*(g2.g2') + B2)
// set==0 additionally folds LamU[c][m] += sum_n Kzx[m][n]*Y[n][c] via shuffles+atomics.
__global__ __launch_bounds__(256) void k_gram(const float* __restrict__ G1, const float* __restrict__ G2,
    const float* __restrict__ Base, const float* __restrict__ Y,
    float* __restrict__ Kzx, float* __restrict__ Kzz, float* __restrict__ Kxz,
    float* __restrict__ LamU)
{
  int z = blockIdx.z, set = z / CC, c = z % CC;
  int colsN = (set == 0) ? NX : MZ;
  if ((int)blockIdx.x * 16 >= colsN) return;
  int rowOff = (set == 2) ? NX+MZ : NX;
  int colOff = (set == 0) ? 0 : NX;
  unsigned baseOff = (set == 0) ? BASE_ZX : (set == 1 ? BASE_ZZ : BASE_TZ);
  float* outp = (set == 0) ? Kzx + c*MZ*NX : (set == 1 ? Kzz + c*MZ*MZ : Kxz + c*TN*MZ);
  __shared__ float g1r[16*132], g2r[16*132], g1c[16*132], g2c[16*132];
  int tid = threadIdx.x, m0 = blockIdx.y*16, n0 = blockIdx.x*16;
  for (int idx = tid; idx < 2048; idx += 256) {
    int r = idx >> 7, hh = idx & 127;
    int sr = rowOff + m0 + r, sc = colOff + n0 + r;
    g1r[r*132+hh] = G1[(sr*CC + c)*H + hh]; g2r[r*132+hh] = G2[(sr*CC + c)*H + hh];
    g1c[r*132+hh] = G1[(sc*CC + c)*H + hh]; g2c[r*132+hh] = G2[(sc*CC + c)*H + hh];
  }
  __syncthreads();
  int ty = tid >> 4, tx = tid & 15;
  const float4* p1 = (const float4*)(g1r + ty*132);
  const float4* p2 = (const float4*)(g1c + tx*132);
  const float4* p3 = (const float4*)(g2r + ty*132);
  const float4* p4 = (const float4*)(g2c + tx*132);
  float dg1 = 0, dg2 = 0;
  #pragma unroll 8
  for (int q = 0; q < 32; ++q) {
    float4 a = p1[q], b = p2[q]; dg1 += a.x*b.x + a.y*b.y + a.z*b.z + a.w*b.w;
    float4 e = p3[q], f = p4[q]; dg2 += e.x*f.x + e.y*f.y + e.z*f.z + e.w*f.w;
  }
  int m = m0 + ty, n = n0 + tx;
  const float* Bp = Base + baseOff;
  int area = 128 * colsN;
  float b0 = Bp[m*colsN + n], b1v = Bp[area + m*colsN + n], b2v = Bp[2*area + m*colsN + n];
  float val = SCALE * (b0*dg1 + b1v*dg2 + b2v);
  outp[m*colsN + n] = val;
  if (set == 0) {
    float lam = val * Y[n*CC + c] * INV_S2;
    lam += __shfl_xor(lam, 1, 64); lam += __shfl_xor(lam, 2, 64);
    lam += __shfl_xor(lam, 4, 64); lam += __shfl_xor(lam, 8, 64);
    if (tx == 0) atomicAdd(&LamU[c*MZ + m], lam);
  }
}

__device__ __forceinline__ float blockReduce128(float v, float* red, int h) {
  #pragma unroll
  for (int off = 32; off > 0; off >>= 1) v += __shfl_down(v, off, 64);
  if ((h & 63) == 0) red[h >> 6] = v;
  __syncthreads();
  float r = red[0] + red[1];
  __syncthreads();
  return r;
}

// Kxx_diag[c][t]; one block per test sample.
__global__ __launch_bounds__(128) void k_kxxd(const float* __restrict__ XS, const float* __restrict__ A1,
    const float* __restrict__ A2, const float* __restrict__ G1, const float* __restrict__ G2,
    float* __restrict__ Kxxd)
{
  int t = blockIdx.x, h = threadIdx.x, s = NX + MZ + t;
  __shared__ float red[2];
  float xv = XS[s*DD+h], a1v = A1[s*H+h], a2v = A2[s*H+h];
  float nx  = blockReduce128(xv*xv,  red, h);
  float na1 = blockReduce128(a1v*a1v, red, h);
  float na2 = blockReduce128(a2v*a2v, red, h);
  for (int c = 0; c < CC; ++c) {
    float g1 = G1[(s*CC+c)*H+h], g2 = G2[(s*CC+c)*H+h];
    float n1 = blockReduce128(g1*g1, red, h);
    float n2 = blockReduce128(g2*g2, red, h);
    if (h == 0) Kxxd[c*TN + t] = SCALE * ((1.0f+nx)*n1 + (1.0f+na1)*n2 + (1.0f+na2));
  }
}

// KzzB = Kzz + Kzx Kzx^T / sigma2 + 2*JIT*I ; Kzzj = Kzz + JIT*I
__global__ __launch_bounds__(256) void k_kzzb(const float* __restrict__ Kzx, const float* __restrict__ Kzz,
    float* __restrict__ Kzzj, float* __restrict__ KzzB)
{
  int c = blockIdx.z, m0 = blockIdx.y*16, k0 = blockIdx.x*16;
  int tid = threadIdx.x, ty = tid >> 4, tx = tid & 15;
  __shared__ float Am[16*17], Ak[16*17];
  const float* Kc = Kzx + c*MZ*NX;
  float acc = 0;
  for (int nc = 0; nc < NX; nc += 16) {
    Am[ty*17+tx] = Kc[(m0+ty)*NX + nc + tx];
    Ak[ty*17+tx] = Kc[(k0+ty)*NX + nc + tx];
    __syncthreads();
    #pragma unroll
    for (int p = 0; p < 16; ++p) acc += Am[ty*17+p] * Ak[tx*17+p];
    __syncthreads();
  }
  int m = m0+ty, k = k0+tx, idx = c*MZ*MZ + m*MZ + k;
  float kzz = Kzz[idx];
  float dia = (m == k) ? 1.0f : 0.0f;
  Kzzj[idx] = kzz + dia*JIT;
  KzzB[idx] = kzz + acc*INV_S2 + dia*2.0f*JIT;
}

// Blocked (rank-4) Cholesky, in-LDS, col-major. Alias-free trailing update via separate
// pan[] array + 8-wide batched rmw. Folds the ylam forward-substitution (which==1).
// Writes Lpan (panel float4 layout: [jb][i] = L[i][4jb..4jb+3]) + invd + ylam.
__global__ __launch_bounds__(512) void k_chol(const float* __restrict__ Kzzj, const float* __restrict__ KzzB,
    float* __restrict__ Lpan, float* __restrict__ invd,
    const float* __restrict__ LamU, float* __restrict__ ylam)
{
  int which = blockIdx.x & 1, c = blockIdx.x >> 1;
  const float* Ain = (which ? KzzB : Kzzj) + c*MZ*MZ;
  float4* LpB = (float4*)(Lpan + (size_t)(which*CC + c)*MZ*MZ);
  float* invB = invd + (which*CC + c)*MZ;
  __shared__ float As[MZ*MZ];    // col-major; input symmetric so straight copy is fine
  __shared__ float4 pan[MZ];     // scaled panel (separate object -> no alias with As)
  __shared__ float bs[MZ];       // running RHS residual for ylam
  __shared__ float ys[MZ];       // ylam solution
  int tid = threadIdx.x;
  int i = tid & 127, kh = tid >> 7;   // kh in 0..3
  {
    float4* d4 = (float4*)As; const float4* s4 = (const float4*)Ain;
    for (int idx = tid; idx < MZ*MZ/4; idx += 512) d4[idx] = s4[idx];
  }
  if (tid < MZ) bs[tid] = which ? LamU[c*MZ + tid] : 0.0f;
  __syncthreads();
  for (int j = 0; j < MZ; j += 4) {
    // raw (post-update) values of current 4 columns at own row + diag block + rhs
    float r0 = As[(j+0)*MZ + i], r1 = As[(j+1)*MZ + i], r2 = As[(j+2)*MZ + i], r3 = As[(j+3)*MZ + i];
    float a00 = As[j*MZ+j];
    float a10 = As[j*MZ+j+1], a20 = As[j*MZ+j+2], a30 = As[j*MZ+j+3];
    float a11 = As[(j+1)*MZ+j+1], a21 = As[(j+1)*MZ+j+2], a31 = As[(j+1)*MZ+j+3];
    float a22 = As[(j+2)*MZ+j+2], a32 = As[(j+2)*MZ+j+3];
    float a33 = As[(j+3)*MZ+j+3];
    float bj0 = bs[j], bj1 = bs[j+1], bj2 = bs[j+2], bj3 = bs[j+3];
    float d0 = sqrtf(a00), id0 = 1.0f/d0;
    float l10 = a10*id0, l20 = a20*id0, l30 = a30*id0;
    float d1 = sqrtf(a11 - l10*l10), id1 = 1.0f/d1;
    float l21 = (a21 - l20*l10)*id1, l31 = (a31 - l30*l10)*id1;
    float d2 = sqrtf(a22 - l20*l20 - l21*l21), id2 = 1.0f/d2;
    float l32 = (a32 - l30*l20 - l31*l21)*id2;
    float d3 = sqrtf(a33 - l30*l30 - l31*l31 - l32*l32), id3 = 1.0f/d3;
    float c0 = r0*id0;
    float c1 = (r1 - c0*l10)*id1;
    float c2 = (r2 - c0*l20 - c1*l21)*id2;
    float c3 = (r3 - c0*l30 - c1*l31 - c2*l32)*id3;
    // ylam chain (identical recurrence, one extra "column")
    float y0 = bj0*id0;
    float y1 = (bj1 - l10*y0)*id1;
    float y2 = (bj2 - l20*y0 - l21*y1)*id2;
    float y3 = (bj3 - l30*y0 - l31*y1 - l32*y2)*id3;
    if (kh == 0) {
      pan[i] = make_float4(c0, c1, c2, c3);
      LpB[(j>>2)*MZ + i] = make_float4(c0, c1, c2, c3);
      if (i == j) {
        invB[j] = id0; invB[j+1] = id1; invB[j+2] = id2; invB[j+3] = id3;
        ys[j] = y0; ys[j+1] = y1; ys[j+2] = y2; ys[j+3] = y3;
      }
      if (i >= j+4) bs[i] -= c0*y0 + c1*y1 + c2*y2 + c3*y3;   // thread-local c = L[i][j..j+3]
    }
    __syncthreads();   // pan visible; bs updates done
    // trailing rank-4 update, batched 8-wide (loads pipeline; pan!=As so no alias stall)
    for (int kb = j + 4 + kh; kb < MZ; kb += 32) {
      float4 pv[8]; float av[8];
      #pragma unroll
      for (int q = 0; q < 8; ++q) {
        int k = kb + 4*q;
        if (k < MZ) { pv[q] = pan[k]; av[q] = As[k*MZ + i]; }
      }
      #pragma unroll
      for (int q = 0; q < 8; ++q) {
        int k = kb + 4*q;
        if (k < MZ) As[k*MZ + i] = av[q] - (c0*pv[q].x + c1*pv[q].y + c2*pv[q].z + c3*pv[q].w);
      }
    }
    __syncthreads();   // trailing writes visible before next step's reads
  }
  if (which && tid < MZ) ylam[c*MZ + tid] = ys[tid];
}

// ----------------------------------------------------------------------------
// Forward substitution L W = Kzxt — 4-wave cooperative, RHS in NAMED registers.
// Rule #20: local arrays land in scratch (SROA runs before unrolling), so the
// 32 per-thread RHS values are 32 named floats via token-pasting macros.
// grid 40 = (c, which, half); 256 threads; lane owns column tt = half*64+lane;
// wave w owns row-groups g = 4s+w (s static 0..7) -> rows 4g..4g+3.
// One barrier per step (parity-double-buffered ysh is race-free: the barrier in
// step JB+1 orders UPD(JB) reads before DIAG(JB+2) writes of the same parity).
// ----------------------------------------------------------------------------
#define B(S,Q) B_##S##_##Q

#define BLOAD(S) { float4 v = src[4*(S)+w];                                   \
    B(S,0) = v.x; B(S,1) = v.y; B(S,2) = v.z; B(S,3) = v.w; }

#define UPD(JB, S)                                                            \
    if (4*(S)+w > (JB)) {                                                     \
      int base_ = (JB)*MZ + (4*(S)+w)*4;                                      \
      float4 l0 = Ls[base_+0], l1 = Ls[base_+1];                              \
      float4 l2 = Ls[base_+2], l3 = Ls[base_+3];                              \
      B(S,0) -= l0.x*y0 + l0.y*y1 + l0.z*y2 + l0.w*y3;                        \
      B(S,1) -= l1.x*y0 + l1.y*y1 + l1.z*y2 + l1.w*y3;                        \
      B(S,2) -= l2.x*y0 + l2.y*y1 + l2.z*y2 + l2.w*y3;                        \
      B(S,3) -= l3.x*y0 + l3.y*y1 + l3.z*y2 + l3.w*y3;                        \
    }

#define STEP(JB, S0, JW)                                                      \
  {                                                                           \
    if (w == (JW)) {                                                          \
      const int j_ = (JB)*4;                                                  \
      float4 q1 = Ls[(JB)*MZ + j_+1];                                         \
      float4 q2 = Ls[(JB)*MZ + j_+2];                                         \
      float4 q3 = Ls[(JB)*MZ + j_+3];                                         \
      float yy0 = B(S0,0)*invS[j_];                                           \
      float yy1 = (B(S0,1) - q1.x*yy0)*invS[j_+1];                            \
      float yy2 = (B(S0,2) - q2.x*yy0 - q2.y*yy1)*invS[j_+2];                 \
      float yy3 = (B(S0,3) - q3.x*yy0 - q3.y*yy1 - q3.z*yy2)*invS[j_+3];      \
      ysh[(JB)&1][0][lane] = yy0; ysh[(JB)&1][1][lane] = yy1;                 \
      ysh[(JB)&1][2][lane] = yy2; ysh[(JB)&1][3][lane] = yy3;                 \
      sq += yy0*yy0 + yy1*yy1 + yy2*yy2 + yy3*yy3;                            \
      fm += yy0*ylS[j_] + yy1*ylS[j_+1] + yy2*ylS[j_+2] + yy3*ylS[j_+3];      \
    }                                                                         \
    __syncthreads();                                                          \
    y0 = ysh[(JB)&1][0][lane]; y1 = ysh[(JB)&1][1][lane];                     \
    y2 = ysh[(JB)&1][2][lane]; y3 = ysh[(JB)&1][3][lane];                     \
    UPD(JB,0) UPD(JB,1) UPD(JB,2) UPD(JB,3)                                   \
    UPD(JB,4) UPD(JB,5) UPD(JB,6) UPD(JB,7)                                   \
  }

__global__ __launch_bounds__(256) void k_subst(const float* __restrict__ Kxz,
    const float* __restrict__ Lpan, const float* __restrict__ invd,
    const float* __restrict__ ylam, float* __restrict__ ssq, float* __restrict__ fmean)
{
  int half  = blockIdx.x & 1;
  int which = (blockIdx.x >> 1) & 1;
  int c     = blockIdx.x >> 2;
  const float4* LpB = (const float4*)(Lpan + (size_t)(which*CC + c)*MZ*MZ);
  const float*  invB = invd + (which*CC + c)*MZ;
  const float*  ylB  = ylam + c*MZ;
  int tid = threadIdx.x, lane = tid & 63, w = tid >> 6;
  __shared__ float4 Ls[32*MZ];          // 64 KiB: all 32 panels [jb*128 + i]
  __shared__ float  ysh[2][4][64];      // parity-double-buffered y broadcast
  __shared__ float  invS[MZ], ylS[MZ];
  __shared__ float  sqp[4][64], fmp[4][64];
  if (tid < MZ) { invS[tid] = invB[tid]; ylS[tid] = ylB[tid]; }
  int tt = half*64 + lane;
  const float4* src = (const float4*)(Kxz + (size_t)c*TN*MZ + (size_t)tt*MZ);
  float B_0_0,B_0_1,B_0_2,B_0_3, B_1_0,B_1_1,B_1_2,B_1_3;
  float B_2_0,B_2_1,B_2_2,B_2_3, B_3_0,B_3_1,B_3_2,B_3_3;
  float B_4_0,B_4_1,B_4_2,B_4_3, B_5_0,B_5_1,B_5_2,B_5_3;
  float B_6_0,B_6_1,B_6_2,B_6_3, B_7_0,B_7_1,B_7_2,B_7_3;
  BLOAD(0) BLOAD(1) BLOAD(2) BLOAD(3) BLOAD(4) BLOAD(5) BLOAD(6) BLOAD(7)
  // stage all L panels: 4096 float4 / 256 threads = 16 each, coalesced
  #pragma unroll
  for (int q = 0; q < 16; ++q) Ls[tid + 256*q] = LpB[tid + 256*q];
  __syncthreads();
  float sq = 0.0f, fm = 0.0f;
  float y0, y1, y2, y3;
  STEP(0,0,0)  STEP(1,0,1)  STEP(2,0,2)  STEP(3,0,3)
  STEP(4,1,0)  STEP(5,1,1)  STEP(6,1,2)  STEP(7,1,3)
  STEP(8,2,0)  STEP(9,2,1)  STEP(10,2,2) STEP(11,2,3)
  STEP(12,3,0) STEP(13,3,1) STEP(14,3,2) STEP(15,3,3)
  STEP(16,4,0) STEP(17,4,1) STEP(18,4,2) STEP(19,4,3)
  STEP(20,5,0) STEP(21,5,1) STEP(22,5,2) STEP(23,5,3)
  STEP(24,6,0) STEP(25,6,1) STEP(26,6,2) STEP(27,6,3)
  STEP(28,7,0) STEP(29,7,1) STEP(30,7,2) STEP(31,7,3)
  sqp[w][lane] = sq; fmp[w][lane] = fm;
  __syncthreads();
  if (tid < 64) {
    float s = sqp[0][tid] + sqp[1][tid] + sqp[2][tid] + sqp[3][tid];
    ssq[(which*CC + c)*TN + half*64 + tid] = s;
    if (which) {
      float f = fmp[0][tid] + fmp[1][tid] + fmp[2][tid] + fmp[3][tid];
      fmean[c*TN + half*64 + tid] = f;
    }
  }
}
#undef STEP
#undef UPD
#undef BLOAD
#undef B

// out[0][t][c] = f_mean ; out[1][t][c] = f_var.T = Kxx - sum(Am^2) + sum(Ab^2)
__global__ __launch_bounds__(256) void k_final(const float* __restrict__ fmean, const float* __restrict__ Kxxd,
    const float* __restrict__ ssq, float* __restrict__ out)
{
  int idx = blockIdx.x*256 + threadIdx.x;
  if (idx >= TN*CC) return;
  int t = idx / CC, c = idx % CC;
  out[idx] = fmean[c*TN + t];
  out[TN*CC + idx] = Kxxd[c*TN + t] - ssq[c*TN + t] + ssq[CC*TN + c*TN + t];
}

extern "C" void kernel_launch(void* const* d_in, const int* in_sizes, int n_in,
                              void* d_out, int out_size, void* d_ws, size_t ws_size,
                              hipStream_t stream) {
  (void)in_sizes; (void)n_in; (void)out_size; (void)ws_size;
  const float* X  = (const float*)d_in[0];
  const float* Y  = (const float*)d_in[1];
  const float* Z  = (const float*)d_in[2];
  const float* Xt = (const float*)d_in[3];
  const float* W1 = (const float*)d_in[4];
  const float* b1 = (const float*)d_in[5];
  const float* W2 = (const float*)d_in[6];
  const float* b2 = (const float*)d_in[7];
  const float* W3 = (const float*)d_in[8];
  float* ws  = (float*)d_ws;
  float* out = (float*)d_out;

  float* XS   = ws + OFF_XS;
  float* A1   = ws + OFF_A1;
  float* A2   = ws + OFF_A2;
  float* G1   = ws + OFF_G1;
  float* G2   = ws + OFF_G2;
  float* W2T  = ws + OFF_W2T;
  float* Base = ws + OFF_BASE;
  float* Kzx  = ws + OFF_KZX;
  float* Kzz  = ws + OFF_KZZ;
  float* Kxz  = ws + OFF_KXZ;
  float* Kxxd = ws + OFF_KXXD;
  float* Kzzj = ws + OFF_KZZJ;
  float* KzzB = ws + OFF_KZZB;
  float* LamU = ws + OFF_LAMU;
  float* Lpan = ws + OFF_LPAN;
  float* invd = ws + OFF_INVD;
  float* ylam = ws + OFF_YLAM;
  float* ssq  = ws + OFF_SSQ;
  float* fmean= ws + OFF_FMEAN;

  k_w2t<<<128, 128, 0, stream>>>(W2, W2T, LamU);
  k_features<<<S_TOT, 128, 0, stream>>>(X, Z, Xt, W1, b1, W2, b2, W3, W2T, XS, A1, A2, G1, G2);
  k_base<<<dim3(16, 8, 3), 256, 0, stream>>>(XS, A1, A2, Base);
  k_gram<<<dim3(16, 8, 3*CC), 256, 0, stream>>>(G1, G2, Base, Y, Kzx, Kzz, Kxz, LamU);
  k_kxxd<<<TN, 128, 0, stream>>>(XS, A1, A2, G1, G2, Kxxd);
  k_kzzb<<<dim3(8, 8, CC), 256, 0, stream>>>(Kzx, Kzz, Kzzj, KzzB);
  k_chol<<<2*CC, 512, 0, stream>>>(Kzzj, KzzB, Lpan, invd, LamU, ylam);
  k_subst<<<4*CC, 256, 0, stream>>>(Kxz, Lpan, invd, ylam, ssq, fmean);
  k_final<<<(TN*CC + 255)/256, 256, 0, stream>>>(fmean, Kxxd, ssq, out);
}

// Round 9
// 213.314 us; speedup vs baseline: 1.0245x; 1.0245x over previous
//
#include <hip/hip_runtime.h>

// NTK-SVGP forward: D=H=128, C=10, N=256, M=128, T=128, sigma2=1, delta=1
#define H 128
#define DD 128
#define CC 10
#define NX 256
#define MZ 128
#define TN 128
#define S_TOT 512   // samples: X[0..255], Z[256..383], X_test[384..511]
#define SCALE (1.0f/256.0f)   // 1/(delta*N)
#define JIT 1e-3f
#define INV_S2 1.0f

// ---------------- ws layout (float offsets) ----------------
#define OFF_XS    0u
#define OFF_A1    (OFF_XS   + S_TOT*DD)
#define OFF_A2    (OFF_A1   + S_TOT*H)
#define OFF_G1    (OFF_A2   + S_TOT*H)
#define OFF_G2    (OFF_G1   + S_TOT*CC*H)
#define OFF_W2T   (OFF_G2   + S_TOT*CC*H)
#define OFF_BASE  (OFF_W2T  + H*H)
#define BASE_ZX   0u
#define BASE_ZZ   (3u*MZ*NX)
#define BASE_TZ   (3u*MZ*NX + 3u*MZ*MZ)
#define OFF_KZX   (OFF_BASE + 3u*MZ*NX + 3u*MZ*MZ + 3u*TN*MZ)
#define OFF_KZZ   (OFF_KZX  + CC*MZ*NX)
#define OFF_KXZ   (OFF_KZZ  + CC*MZ*MZ)
#define OFF_KXXD  (OFF_KXZ  + CC*TN*MZ)
#define OFF_KZZJ  (OFF_KXXD + CC*TN)
#define OFF_KZZB  (OFF_KZZJ + CC*MZ*MZ)
#define OFF_LAMU  (OFF_KZZB + CC*MZ*MZ)
#define OFF_SSQ   (OFF_LAMU + CC*MZ)
#define OFF_FMEAN (OFF_SSQ  + 2u*CC*TN)

__global__ __launch_bounds__(128) void k_w2t(const float* __restrict__ W2, float* __restrict__ W2T,
                                             float* __restrict__ LamU) {
  int k = blockIdx.x, h = threadIdx.x;
  W2T[k*H + h] = W2[h*H + k];
  if (k < CC) LamU[k*MZ + h] = 0.0f;   // zero for k_gram's atomic accumulation
}

// Per-sample forward + backprop features. One block per sample, 128 threads.
__global__ __launch_bounds__(128) void k_features(
    const float* __restrict__ X, const float* __restrict__ Z, const float* __restrict__ Xt,
    const float* __restrict__ W1, const float* __restrict__ b1,
    const float* __restrict__ W2, const float* __restrict__ b2,
    const float* __restrict__ W3, const float* __restrict__ W2T,
    float* __restrict__ XS, float* __restrict__ A1, float* __restrict__ A2,
    float* __restrict__ G1, float* __restrict__ G2)
{
  int s = blockIdx.x, h = threadIdx.x;
  const float* xin = (s < NX) ? X + s*DD : (s < NX+MZ ? Z + (s-NX)*DD : Xt + (s-NX-MZ)*DD);
  __shared__ float xs[DD], a1s[H], g2s[CC*H];
  float xv = xin[h];
  xs[h] = xv; XS[s*DD + h] = xv;
  __syncthreads();
  float acc = b1[h];
  #pragma unroll 4
  for (int d0 = 0; d0 < DD; ++d0) acc += xs[d0] * W1[d0*H + h];   // coalesced over h
  float a1 = tanhf(acc);
  a1s[h] = a1; A1[s*H + h] = a1;
  __syncthreads();
  acc = b2[h];
  #pragma unroll 4
  for (int d0 = 0; d0 < H; ++d0) acc += a1s[d0] * W2[d0*H + h];
  float a2 = tanhf(acc);
  A2[s*H + h] = a2;
  float t2 = 1.0f - a2*a2;
  #pragma unroll
  for (int c = 0; c < CC; ++c) {
    float g2 = W3[h*CC + c] * t2;
    g2s[c*H + h] = g2;
    G2[(s*CC + c)*H + h] = g2;
  }
  __syncthreads();
  float t1 = 1.0f - a1*a1;
  float accs[CC];
  #pragma unroll
  for (int c = 0; c < CC; ++c) accs[c] = 0.0f;
  for (int k = 0; k < H; ++k) {
    float w = W2T[k*H + h];        // coalesced over h
    #pragma unroll
    for (int c = 0; c < CC; ++c) accs[c] += w * g2s[c*H + k];   // broadcast
  }
  #pragma unroll
  for (int c = 0; c < CC; ++c) G1[(s*CC + c)*H + h] = t1 * accs[c];
}

// Class-independent base dot products: 1+x.x', 1+a1.a1', 1+a2.a2'
__global__ __launch_bounds__(256) void k_base(const float* __restrict__ XS,
    const float* __restrict__ A1, const float* __restrict__ A2, float* __restrict__ Base)
{
  int set = blockIdx.z;
  int colsN = (set == 0) ? NX : MZ;
  if ((int)blockIdx.x * 16 >= colsN) return;
  int rowOff = (set == 2) ? NX+MZ : NX;
  int colOff = (set == 0) ? 0 : NX;
  unsigned baseOff = (set == 0) ? BASE_ZX : (set == 1 ? BASE_ZZ : BASE_TZ);
  __shared__ float rx[16*132], r1[16*132], r2[16*132], cxs[16*132], c1s[16*132], c2s[16*132];
  int tid = threadIdx.x, m0 = blockIdx.y*16, n0 = blockIdx.x*16;
  for (int idx = tid; idx < 16*128; idx += 256) {
    int r = idx >> 7, hh = idx & 127;
    int sr = rowOff + m0 + r, sc = colOff + n0 + r;
    rx [r*132+hh] = XS[sr*DD+hh]; r1[r*132+hh] = A1[sr*H+hh]; r2[r*132+hh] = A2[sr*H+hh];
    cxs[r*132+hh] = XS[sc*DD+hh]; c1s[r*132+hh] = A1[sc*H+hh]; c2s[r*132+hh] = A2[sc*H+hh];
  }
  __syncthreads();
  int ty = tid >> 4, tx = tid & 15;
  const float4* pa = (const float4*)(rx  + ty*132);
  const float4* pb = (const float4*)(cxs + tx*132);
  const float4* pc = (const float4*)(r1  + ty*132);
  const float4* pd = (const float4*)(c1s + tx*132);
  const float4* pe = (const float4*)(r2  + ty*132);
  const float4* pf = (const float4*)(c2s + tx*132);
  float d0 = 0, d1 = 0, d2 = 0;
  #pragma unroll 8
  for (int q = 0; q < 32; ++q) {
    float4 a = pa[q], b = pb[q]; d0 += a.x*b.x + a.y*b.y + a.z*b.z + a.w*b.w;
    float4 c = pc[q], d = pd[q]; d1 += c.x*d.x + c.y*d.y + c.z*d.z + c.w*d.w;
    float4 e = pe[q], f = pf[q]; d2 += e.x*f.x + e.y*f.y + e.z*f.z + e.w*f.w;
  }
  int m = m0 + ty, n = n0 + tx;
  float* Bp = Base + baseOff;
  int area = 128 * colsN;
  Bp[0*area + m*colsN + n] = 1.0f + d0;
  Bp[1*area + m*colsN + n] = 1.0f + d1;
  Bp[2*area + m*colsN + n] = 1.0f + d2;
}

// Per-class NTK gram: K = SCALE*(B0*(g1.g1') + B1*(g2.g2') + B2)
// set==0 additionally folds LamU[c][m] += sum_n Kzx[m][n]*Y[n][c] via shuffles+atomics.
__global__ __launch_bounds__(256) void k_gram(const float* __restrict__ G1, const float* __restrict__ G2,
    const float* __restrict__ Base, const float* __restrict__ Y,
    float* __restrict__ Kzx, float* __restrict__ Kzz, float* __restrict__ Kxz,
    float* __restrict__ LamU)
{
  int z = blockIdx.z, set = z / CC, c = z % CC;
  int colsN = (set == 0) ? NX : MZ;
  if ((int)blockIdx.x * 16 >= colsN) return;
  int rowOff = (set == 2) ? NX+MZ : NX;
  int colOff = (set == 0) ? 0 : NX;
  unsigned baseOff = (set == 0) ? BASE_ZX : (set == 1 ? BASE_ZZ : BASE_TZ);
  float* outp = (set == 0) ? Kzx + c*MZ*NX : (set == 1 ? Kzz + c*MZ*MZ : Kxz + c*TN*MZ);
  __shared__ float g1r[16*132], g2r[16*132], g1c[16*132], g2c[16*132];
  int tid = threadIdx.x, m0 = blockIdx.y*16, n0 = blockIdx.x*16;
  for (int idx = tid; idx < 2048; idx += 256) {
    int r = idx >> 7, hh = idx & 127;
    int sr = rowOff + m0 + r, sc = colOff + n0 + r;
    g1r[r*132+hh] = G1[(sr*CC + c)*H + hh]; g2r[r*132+hh] = G2[(sr*CC + c)*H + hh];
    g1c[r*132+hh] = G1[(sc*CC + c)*H + hh]; g2c[r*132+hh] = G2[(sc*CC + c)*H + hh];
  }
  __syncthreads();
  int ty = tid >> 4, tx = tid & 15;
  const float4* p1 = (const float4*)(g1r + ty*132);
  const float4* p2 = (const float4*)(g1c + tx*132);
  const float4* p3 = (const float4*)(g2r + ty*132);
  const float4* p4 = (const float4*)(g2c + tx*132);
  float dg1 = 0, dg2 = 0;
  #pragma unroll 8
  for (int q = 0; q < 32; ++q) {
    float4 a = p1[q], b = p2[q]; dg1 += a.x*b.x + a.y*b.y + a.z*b.z + a.w*b.w;
    float4 e = p3[q], f = p4[q]; dg2 += e.x*f.x + e.y*f.y + e.z*f.z + e.w*f.w;
  }
  int m = m0 + ty, n = n0 + tx;
  const float* Bp = Base + baseOff;
  int area = 128 * colsN;
  float b0 = Bp[m*colsN + n], b1v = Bp[area + m*colsN + n], b2v = Bp[2*area + m*colsN + n];
  float val = SCALE * (b0*dg1 + b1v*dg2 + b2v);
  outp[m*colsN + n] = val;
  if (set == 0) {
    float lam = val * Y[n*CC + c] * INV_S2;
    lam += __shfl_xor(lam, 1, 64); lam += __shfl_xor(lam, 2, 64);
    lam += __shfl_xor(lam, 4, 64); lam += __shfl_xor(lam, 8, 64);
    if (tx == 0) atomicAdd(&LamU[c*MZ + m], lam);
  }
}

__device__ __forceinline__ float blockReduce128(float v, float* red, int h) {
  #pragma unroll
  for (int off = 32; off > 0; off >>= 1) v += __shfl_down(v, off, 64);
  if ((h & 63) == 0) red[h >> 6] = v;
  __syncthreads();
  float r = red[0] + red[1];
  __syncthreads();
  return r;
}

// Kxx_diag[c][t]; one block per test sample.
__global__ __launch_bounds__(128) void k_kxxd(const float* __restrict__ XS, const float* __restrict__ A1,
    const float* __restrict__ A2, const float* __restrict__ G1, const float* __restrict__ G2,
    float* __restrict__ Kxxd)
{
  int t = blockIdx.x, h = threadIdx.x, s = NX + MZ + t;
  __shared__ float red[2];
  float xv = XS[s*DD+h], a1v = A1[s*H+h], a2v = A2[s*H+h];
  float nx  = blockReduce128(xv*xv,  red, h);
  float na1 = blockReduce128(a1v*a1v, red, h);
  float na2 = blockReduce128(a2v*a2v, red, h);
  for (int c = 0; c < CC; ++c) {
    float g1 = G1[(s*CC+c)*H+h], g2 = G2[(s*CC+c)*H+h];
    float n1 = blockReduce128(g1*g1, red, h);
    float n2 = blockReduce128(g2*g2, red, h);
    if (h == 0) Kxxd[c*TN + t] = SCALE * ((1.0f+nx)*n1 + (1.0f+na1)*n2 + (1.0f+na2));
  }
}

// KzzB = Kzz + Kzx Kzx^T / sigma2 + 2*JIT*I ; Kzzj = Kzz + JIT*I
__global__ __launch_bounds__(256) void k_kzzb(const float* __restrict__ Kzx, const float* __restrict__ Kzz,
    float* __restrict__ Kzzj, float* __restrict__ KzzB)
{
  int c = blockIdx.z, m0 = blockIdx.y*16, k0 = blockIdx.x*16;
  int tid = threadIdx.x, ty = tid >> 4, tx = tid & 15;
  __shared__ float Am[16*17], Ak[16*17];
  const float* Kc = Kzx + c*MZ*NX;
  float acc = 0;
  for (int nc = 0; nc < NX; nc += 16) {
    Am[ty*17+tx] = Kc[(m0+ty)*NX + nc + tx];
    Ak[ty*17+tx] = Kc[(k0+ty)*NX + nc + tx];
    __syncthreads();
    #pragma unroll
    for (int p = 0; p < 16; ++p) acc += Am[ty*17+p] * Ak[tx*17+p];
    __syncthreads();
  }
  int m = m0+ty, k = k0+tx, idx = c*MZ*MZ + m*MZ + k;
  float kzz = Kzz[idx];
  float dia = (m == k) ? 1.0f : 0.0f;
  Kzzj[idx] = kzz + dia*JIT;
  KzzB[idx] = kzz + acc*INV_S2 + dia*2.0f*JIT;
}

// ----------------------------------------------------------------------------
// FUSED: blocked rank-4 Cholesky + ylam forward-subst + full triangular solve
// L W = Kzxt for 128 RHS columns, all in one kernel (k_subst eliminated).
// Per panel j: (a) every thread computes the scalar diag chain; (b) thread t<128
// solves its 4 W-rows from Bres and accumulates sq/fm (fm uses its own y-chain,
// = ylam[j..j+3]); (c) rank-4 trailing update of As (triangle, kh-partitioned)
// and Bres (128x128, thread=(t,kh) owns 32 rows). Bres columns XOR-swizzled:
// col(t,i) = t ^ (i>>2)  -> staging stores, solve reads, and update rmw are all
// <=2 lanes/bank (free). LDS ~133.5 KB (1 block/CU; only 20 blocks).
// ----------------------------------------------------------------------------
__global__ __launch_bounds__(512) void k_chol(const float* __restrict__ Kzzj, const float* __restrict__ KzzB,
    const float* __restrict__ LamU, const float* __restrict__ Kxz,
    float* __restrict__ ssq, float* __restrict__ fmean)
{
  int which = blockIdx.x & 1, c = blockIdx.x >> 1;
  const float* Ain = (which ? KzzB : Kzzj) + c*MZ*MZ;
  const float4* KxzC4 = (const float4*)(Kxz + (size_t)c*TN*MZ);
  __shared__ float As[MZ*MZ];     // 64 KB col-major working copy (symmetric input)
  __shared__ float Bres[MZ*MZ];   // 64 KB RHS residual, col-swizzled
  __shared__ float4 pan[MZ];      // scaled panel L[i][j..j+3]
  __shared__ float wrow[4][MZ];   // solved W rows (per column t)
  __shared__ float bs[MZ];        // ylam RHS residual
  int tid = threadIdx.x;
  int i = tid & 127, kh = tid >> 7;   // i = row (and column-owner t), kh in 0..3
  {
    float4* d4 = (float4*)As; const float4* s4 = (const float4*)Ain;
    #pragma unroll
    for (int r = 0; r < 8; ++r) d4[tid + 512*r] = s4[tid + 512*r];
  }
  // Stage Bres[i][col(t,i)] = Kxz[t][i]; linear coalesced read, swizzled store
  #pragma unroll
  for (int r = 0; r < 8; ++r) {
    int f = tid + 512*r;
    int t = f >> 5, i4 = f & 31;
    float4 v = KxzC4[f];
    int col = t ^ i4;
    Bres[(4*i4+0)*MZ + col] = v.x;
    Bres[(4*i4+1)*MZ + col] = v.y;
    Bres[(4*i4+2)*MZ + col] = v.z;
    Bres[(4*i4+3)*MZ + col] = v.w;
  }
  if (tid < MZ) bs[tid] = which ? LamU[c*MZ + tid] : 0.0f;
  __syncthreads();
  float sq = 0.0f, fm = 0.0f;
  for (int j = 0; j < MZ; j += 4) {
    int jb = j >> 2;
    float r0 = As[(j+0)*MZ + i], r1 = As[(j+1)*MZ + i], r2 = As[(j+2)*MZ + i], r3 = As[(j+3)*MZ + i];
    float a00 = As[j*MZ+j];
    float a10 = As[j*MZ+j+1], a20 = As[j*MZ+j+2], a30 = As[j*MZ+j+3];
    float a11 = As[(j+1)*MZ+j+1], a21 = As[(j+1)*MZ+j+2], a31 = As[(j+1)*MZ+j+3];
    float a22 = As[(j+2)*MZ+j+2], a32 = As[(j+2)*MZ+j+3];
    float a33 = As[(j+3)*MZ+j+3];
    float bj0 = bs[j], bj1 = bs[j+1], bj2 = bs[j+2], bj3 = bs[j+3];
    float d0 = sqrtf(a00), id0 = 1.0f/d0;
    float l10 = a10*id0, l20 = a20*id0, l30 = a30*id0;
    float d1 = sqrtf(a11 - l10*l10), id1 = 1.0f/d1;
    float l21 = (a21 - l20*l10)*id1, l31 = (a31 - l30*l10)*id1;
    float d2 = sqrtf(a22 - l20*l20 - l21*l21), id2 = 1.0f/d2;
    float l32 = (a32 - l30*l20 - l31*l21)*id2;
    float d3 = sqrtf(a33 - l30*l30 - l31*l31 - l32*l32), id3 = 1.0f/d3;
    float c0 = r0*id0;
    float c1 = (r1 - c0*l10)*id1;
    float c2 = (r2 - c0*l20 - c1*l21)*id2;
    float c3 = (r3 - c0*l30 - c1*l31 - c2*l32)*id3;
    // ylam chain (all threads; these ARE ylam[j..j+3] final values)
    float y0 = bj0*id0;
    float y1 = (bj1 - l10*y0)*id1;
    float y2 = (bj2 - l20*y0 - l21*y1)*id2;
    float y3 = (bj3 - l30*y0 - l31*y1 - l32*y2)*id3;
    if (kh == 0) {
      pan[i] = make_float4(c0, c1, c2, c3);
      // W-solve for column t = i (reads stable since last barrier)
      int colw = i ^ jb;
      float bb0 = Bres[(j+0)*MZ + colw];
      float bb1 = Bres[(j+1)*MZ + colw];
      float bb2 = Bres[(j+2)*MZ + colw];
      float bb3 = Bres[(j+3)*MZ + colw];
      float w0 = bb0*id0;
      float w1 = (bb1 - l10*w0)*id1;
      float w2 = (bb2 - l20*w0 - l21*w1)*id2;
      float w3 = (bb3 - l30*w0 - l31*w1 - l32*w2)*id3;
      wrow[0][i] = w0; wrow[1][i] = w1; wrow[2][i] = w2; wrow[3][i] = w3;
      sq += w0*w0 + w1*w1 + w2*w2 + w3*w3;
      fm += w0*y0 + w1*y1 + w2*y2 + w3*y3;
      if (i >= j+4) bs[i] -= c0*y0 + c1*y1 + c2*y2 + c3*y3;   // c = L[i][j..j+3]
    }
    __syncthreads();   // pan/wrow visible; bs updates done
    // trailing rank-4 update of As (kh-partitioned, 8-wide batch)
    for (int kb = j + 4 + kh; kb < MZ; kb += 32) {
      float4 pv[8]; float av[8];
      #pragma unroll
      for (int q = 0; q < 8; ++q) {
        int k = kb + 4*q;
        if (k < MZ) { pv[q] = pan[k]; av[q] = As[k*MZ + i]; }
      }
      #pragma unroll
      for (int q = 0; q < 8; ++q) {
        int k = kb + 4*q;
        if (k < MZ) As[k*MZ + i] = av[q] - (c0*pv[q].x + c1*pv[q].y + c2*pv[q].z + c3*pv[q].w);
      }
    }
    // trailing rank-4 update of Bres: thread (t=i, kh) owns rows [kh*32, kh*32+32)
    {
      float u0 = wrow[0][i], u1 = wrow[1][i], u2 = wrow[2][i], u3 = wrow[3][i];
      int ibase = kh*32;
      for (int ib = ibase; ib < ibase+32; ib += 8) {
        float4 pv[8]; float bv[8];
        #pragma unroll
        for (int q = 0; q < 8; ++q) {
          int ii = ib + q;
          if (ii >= j+4) { pv[q] = pan[ii]; bv[q] = Bres[ii*MZ + (i ^ (ii>>2))]; }
        }
        #pragma unroll
        for (int q = 0; q < 8; ++q) {
          int ii = ib + q;
          if (ii >= j+4) Bres[ii*MZ + (i ^ (ii>>2))] = bv[q] - (pv[q].x*u0 + pv[q].y*u1 + pv[q].z*u2 + pv[q].w*u3);
        }
      }
    }
    __syncthreads();   // trailing writes visible before next panel's reads
  }
  if (tid < MZ) {
    ssq[(which*CC + c)*TN + tid] = sq;
    if (which) fmean[c*TN + tid] = fm;
  }
}

// out[0][t][c] = f_mean ; out[1][t][c] = f_var.T = Kxx - sum(Am^2) + sum(Ab^2)
__global__ __launch_bounds__(256) void k_final(const float* __restrict__ fmean, const float* __restrict__ Kxxd,
    const float* __restrict__ ssq, float* __restrict__ out)
{
  int idx = blockIdx.x*256 + threadIdx.x;
  if (idx >= TN*CC) return;
  int t = idx / CC, c = idx % CC;
  out[idx] = fmean[c*TN + t];
  out[TN*CC + idx] = Kxxd[c*TN + t] - ssq[c*TN + t] + ssq[CC*TN + c*TN + t];
}

extern "C" void kernel_launch(void* const* d_in, const int* in_sizes, int n_in,
                              void* d_out, int out_size, void* d_ws, size_t ws_size,
                              hipStream_t stream) {
  (void)in_sizes; (void)n_in; (void)out_size; (void)ws_size;
  const float* X  = (const float*)d_in[0];
  const float* Y  = (const float*)d_in[1];
  const float* Z  = (const float*)d_in[2];
  const float* Xt = (const float*)d_in[3];
  const float* W1 = (const float*)d_in[4];
  const float* b1 = (const float*)d_in[5];
  const float* W2 = (const float*)d_in[6];
  const float* b2 = (const float*)d_in[7];
  const float* W3 = (const float*)d_in[8];
  float* ws  = (float*)d_ws;
  float* out = (float*)d_out;

  float* XS   = ws + OFF_XS;
  float* A1   = ws + OFF_A1;
  float* A2   = ws + OFF_A2;
  float* G1   = ws + OFF_G1;
  float* G2   = ws + OFF_G2;
  float* W2T  = ws + OFF_W2T;
  float* Base = ws + OFF_BASE;
  float* Kzx  = ws + OFF_KZX;
  float* Kzz  = ws + OFF_KZZ;
  float* Kxz  = ws + OFF_KXZ;
  float* Kxxd = ws + OFF_KXXD;
  float* Kzzj = ws + OFF_KZZJ;
  float* KzzB = ws + OFF_KZZB;
  float* LamU = ws + OFF_LAMU;
  float* ssq  = ws + OFF_SSQ;
  float* fmean= ws + OFF_FMEAN;

  k_w2t<<<128, 128, 0, stream>>>(W2, W2T, LamU);
  k_features<<<S_TOT, 128, 0, stream>>>(X, Z, Xt, W1, b1, W2, b2, W3, W2T, XS, A1, A2, G1, G2);
  k_base<<<dim3(16, 8, 3), 256, 0, stream>>>(XS, A1, A2, Base);
  k_gram<<<dim3(16, 8, 3*CC), 256, 0, stream>>>(G1, G2, Base, Y, Kzx, Kzz, Kxz, LamU);
  k_kxxd<<<TN, 128, 0, stream>>>(XS, A1, A2, G1, G2, Kxxd);
  k_kzzb<<<dim3(8, 8, CC), 256, 0, stream>>>(Kzx, Kzz, Kzzj, KzzB);
  k_chol<<<2*CC, 512, 0, stream>>>(Kzzj, KzzB, LamU, Kxz, ssq, fmean);
  k_final<<<(TN*CC + 255)/256, 256, 0, stream>>>(fmean, Kxxd, ssq, out);
}

// Round 10
// 157.346 us; speedup vs baseline: 1.3889x; 1.3557x over previous
//
#include <hip/hip_runtime.h>

// NTK-SVGP forward: D=H=128, C=10, N=256, M=128, T=128, sigma2=1, delta=1
#define H 128
#define DD 128
#define CC 10
#define NX 256
#define MZ 128
#define TN 128
#define S_TOT 512   // samples: X[0..255], Z[256..383], X_test[384..511]
#define SCALE (1.0f/256.0f)   // 1/(delta*N)
#define JIT 1e-3f
#define INV_S2 1.0f

// ---------------- ws layout (float offsets) ----------------
#define OFF_XS    0u
#define OFF_A1    (OFF_XS   + S_TOT*DD)
#define OFF_A2    (OFF_A1   + S_TOT*H)
#define OFF_G1    (OFF_A2   + S_TOT*H)
#define OFF_G2    (OFF_G1   + S_TOT*CC*H)
#define OFF_W2T   (OFF_G2   + S_TOT*CC*H)
#define OFF_BASE  (OFF_W2T  + H*H)
#define BASE_ZX   0u
#define BASE_ZZ   (3u*MZ*NX)
#define BASE_TZ   (3u*MZ*NX + 3u*MZ*MZ)
#define OFF_KZX   (OFF_BASE + 3u*MZ*NX + 3u*MZ*MZ + 3u*TN*MZ)
#define OFF_KZZ   (OFF_KZX  + CC*MZ*NX)
#define OFF_KXZ   (OFF_KZZ  + CC*MZ*MZ)
#define OFF_KXXD  (OFF_KXZ  + CC*TN*MZ)
#define OFF_KZZJ  (OFF_KXXD + CC*TN)
#define OFF_KZZB  (OFF_KZZJ + CC*MZ*MZ)
#define OFF_LAMU  (OFF_KZZB + CC*MZ*MZ)
#define OFF_SSQ   (OFF_LAMU + CC*MZ)
#define OFF_FMEAN (OFF_SSQ  + 2u*CC*TN)

__global__ __launch_bounds__(128) void k_w2t(const float* __restrict__ W2, float* __restrict__ W2T,
                                             float* __restrict__ LamU) {
  int k = blockIdx.x, h = threadIdx.x;
  W2T[k*H + h] = W2[h*H + k];
  if (k < CC) LamU[k*MZ + h] = 0.0f;   // zero for k_gram's atomic accumulation
}

// Per-sample forward + backprop features. One block per sample, 128 threads.
__global__ __launch_bounds__(128) void k_features(
    const float* __restrict__ X, const float* __restrict__ Z, const float* __restrict__ Xt,
    const float* __restrict__ W1, const float* __restrict__ b1,
    const float* __restrict__ W2, const float* __restrict__ b2,
    const float* __restrict__ W3, const float* __restrict__ W2T,
    float* __restrict__ XS, float* __restrict__ A1, float* __restrict__ A2,
    float* __restrict__ G1, float* __restrict__ G2)
{
  int s = blockIdx.x, h = threadIdx.x;
  const float* xin = (s < NX) ? X + s*DD : (s < NX+MZ ? Z + (s-NX)*DD : Xt + (s-NX-MZ)*DD);
  __shared__ float xs[DD], a1s[H], g2s[CC*H];
  float xv = xin[h];
  xs[h] = xv; XS[s*DD + h] = xv;
  __syncthreads();
  float acc = b1[h];
  #pragma unroll 4
  for (int d0 = 0; d0 < DD; ++d0) acc += xs[d0] * W1[d0*H + h];   // coalesced over h
  float a1 = tanhf(acc);
  a1s[h] = a1; A1[s*H + h] = a1;
  __syncthreads();
  acc = b2[h];
  #pragma unroll 4
  for (int d0 = 0; d0 < H; ++d0) acc += a1s[d0] * W2[d0*H + h];
  float a2 = tanhf(acc);
  A2[s*H + h] = a2;
  float t2 = 1.0f - a2*a2;
  #pragma unroll
  for (int c = 0; c < CC; ++c) {
    float g2 = W3[h*CC + c] * t2;
    g2s[c*H + h] = g2;
    G2[(s*CC + c)*H + h] = g2;
  }
  __syncthreads();
  float t1 = 1.0f - a1*a1;
  float accs[CC];
  #pragma unroll
  for (int c = 0; c < CC; ++c) accs[c] = 0.0f;
  for (int k = 0; k < H; ++k) {
    float w = W2T[k*H + h];        // coalesced over h
    #pragma unroll
    for (int c = 0; c < CC; ++c) accs[c] += w * g2s[c*H + k];   // broadcast
  }
  #pragma unroll
  for (int c = 0; c < CC; ++c) G1[(s*CC + c)*H + h] = t1 * accs[c];
}

// Class-independent base dot products: 1+x.x', 1+a1.a1', 1+a2.a2'
__global__ __launch_bounds__(256) void k_base(const float* __restrict__ XS,
    const float* __restrict__ A1, const float* __restrict__ A2, float* __restrict__ Base)
{
  int set = blockIdx.z;
  int colsN = (set == 0) ? NX : MZ;
  if ((int)blockIdx.x * 16 >= colsN) return;
  int rowOff = (set == 2) ? NX+MZ : NX;
  int colOff = (set == 0) ? 0 : NX;
  unsigned baseOff = (set == 0) ? BASE_ZX : (set == 1 ? BASE_ZZ : BASE_TZ);
  __shared__ float rx[16*132], r1[16*132], r2[16*132], cxs[16*132], c1s[16*132], c2s[16*132];
  int tid = threadIdx.x, m0 = blockIdx.y*16, n0 = blockIdx.x*16;
  for (int idx = tid; idx < 16*128; idx += 256) {
    int r = idx >> 7, hh = idx & 127;
    int sr = rowOff + m0 + r, sc = colOff + n0 + r;
    rx [r*132+hh] = XS[sr*DD+hh]; r1[r*132+hh] = A1[sr*H+hh]; r2[r*132+hh] = A2[sr*H+hh];
    cxs[r*132+hh] = XS[sc*DD+hh]; c1s[r*132+hh] = A1[sc*H+hh]; c2s[r*132+hh] = A2[sc*H+hh];
  }
  __syncthreads();
  int ty = tid >> 4, tx = tid & 15;
  const float4* pa = (const float4*)(rx  + ty*132);
  const float4* pb = (const float4*)(cxs + tx*132);
  const float4* pc = (const float4*)(r1  + ty*132);
  const float4* pd = (const float4*)(c1s + tx*132);
  const float4* pe = (const float4*)(r2  + ty*132);
  const float4* pf = (const float4*)(c2s + tx*132);
  float d0 = 0, d1 = 0, d2 = 0;
  #pragma unroll 8
  for (int q = 0; q < 32; ++q) {
    float4 a = pa[q], b = pb[q]; d0 += a.x*b.x + a.y*b.y + a.z*b.z + a.w*b.w;
    float4 c = pc[q], d = pd[q]; d1 += c.x*d.x + c.y*d.y + c.z*d.z + c.w*d.w;
    float4 e = pe[q], f = pf[q]; d2 += e.x*f.x + e.y*f.y + e.z*f.z + e.w*f.w;
  }
  int m = m0 + ty, n = n0 + tx;
  float* Bp = Base + baseOff;
  int area = 128 * colsN;
  Bp[0*area + m*colsN + n] = 1.0f + d0;
  Bp[1*area + m*colsN + n] = 1.0f + d1;
  Bp[2*area + m*colsN + n] = 1.0f + d2;
}

// Per-class NTK gram: K = SCALE*(B0*(g1.g1') + B1*(g2.g2') + B2)
// set==0 additionally folds LamU[c][m] += sum_n Kzx[m][n]*Y[n][c] via shuffles+atomics.
__global__ __launch_bounds__(256) void k_gram(const float* __restrict__ G1, const float* __restrict__ G2,
    const float* __restrict__ Base, const float* __restrict__ Y,
    float* __restrict__ Kzx, float* __restrict__ Kzz, float* __restrict__ Kxz,
    float* __restrict__ LamU)
{
  int z = blockIdx.z, set = z / CC, c = z % CC;
  int colsN = (set == 0) ? NX : MZ;
  if ((int)blockIdx.x * 16 >= colsN) return;
  int rowOff = (set == 2) ? NX+MZ : NX;
  int colOff = (set == 0) ? 0 : NX;
  unsigned baseOff = (set == 0) ? BASE_ZX : (set == 1 ? BASE_ZZ : BASE_TZ);
  float* outp = (set == 0) ? Kzx + c*MZ*NX : (set == 1 ? Kzz + c*MZ*MZ : Kxz + c*TN*MZ);
  __shared__ float g1r[16*132], g2r[16*132], g1c[16*132], g2c[16*132];
  int tid = threadIdx.x, m0 = blockIdx.y*16, n0 = blockIdx.x*16;
  for (int idx = tid; idx < 2048; idx += 256) {
    int r = idx >> 7, hh = idx & 127;
    int sr = rowOff + m0 + r, sc = colOff + n0 + r;
    g1r[r*132+hh] = G1[(sr*CC + c)*H + hh]; g2r[r*132+hh] = G2[(sr*CC + c)*H + hh];
    g1c[r*132+hh] = G1[(sc*CC + c)*H + hh]; g2c[r*132+hh] = G2[(sc*CC + c)*H + hh];
  }
  __syncthreads();
  int ty = tid >> 4, tx = tid & 15;
  const float4* p1 = (const float4*)(g1r + ty*132);
  const float4* p2 = (const float4*)(g1c + tx*132);
  const float4* p3 = (const float4*)(g2r + ty*132);
  const float4* p4 = (const float4*)(g2c + tx*132);
  float dg1 = 0, dg2 = 0;
  #pragma unroll 8
  for (int q = 0; q < 32; ++q) {
    float4 a = p1[q], b = p2[q]; dg1 += a.x*b.x + a.y*b.y + a.z*b.z + a.w*b.w;
    float4 e = p3[q], f = p4[q]; dg2 += e.x*f.x + e.y*f.y + e.z*f.z + e.w*f.w;
  }
  int m = m0 + ty, n = n0 + tx;
  const float* Bp = Base + baseOff;
  int area = 128 * colsN;
  float b0 = Bp[m*colsN + n], b1v = Bp[area + m*colsN + n], b2v = Bp[2*area + m*colsN + n];
  float val = SCALE * (b0*dg1 + b1v*dg2 + b2v);
  outp[m*colsN + n] = val;
  if (set == 0) {
    float lam = val * Y[n*CC + c] * INV_S2;
    lam += __shfl_xor(lam, 1, 64); lam += __shfl_xor(lam, 2, 64);
    lam += __shfl_xor(lam, 4, 64); lam += __shfl_xor(lam, 8, 64);
    if (tx == 0) atomicAdd(&LamU[c*MZ + m], lam);
  }
}

__device__ __forceinline__ float blockReduce128(float v, float* red, int h) {
  #pragma unroll
  for (int off = 32; off > 0; off >>= 1) v += __shfl_down(v, off, 64);
  if ((h & 63) == 0) red[h >> 6] = v;
  __syncthreads();
  float r = red[0] + red[1];
  __syncthreads();
  return r;
}

// Kxx_diag[c][t]; one block per test sample.
__global__ __launch_bounds__(128) void k_kxxd(const float* __restrict__ XS, const float* __restrict__ A1,
    const float* __restrict__ A2, const float* __restrict__ G1, const float* __restrict__ G2,
    float* __restrict__ Kxxd)
{
  int t = blockIdx.x, h = threadIdx.x, s = NX + MZ + t;
  __shared__ float red[2];
  float xv = XS[s*DD+h], a1v = A1[s*H+h], a2v = A2[s*H+h];
  float nx  = blockReduce128(xv*xv,  red, h);
  float na1 = blockReduce128(a1v*a1v, red, h);
  float na2 = blockReduce128(a2v*a2v, red, h);
  for (int c = 0; c < CC; ++c) {
    float g1 = G1[(s*CC+c)*H+h], g2 = G2[(s*CC+c)*H+h];
    float n1 = blockReduce128(g1*g1, red, h);
    float n2 = blockReduce128(g2*g2, red, h);
    if (h == 0) Kxxd[c*TN + t] = SCALE * ((1.0f+nx)*n1 + (1.0f+na1)*n2 + (1.0f+na2));
  }
}

// KzzB = Kzz + Kzx Kzx^T / sigma2 + 2*JIT*I ; Kzzj = Kzz + JIT*I
__global__ __launch_bounds__(256) void k_kzzb(const float* __restrict__ Kzx, const float* __restrict__ Kzz,
    float* __restrict__ Kzzj, float* __restrict__ KzzB)
{
  int c = blockIdx.z, m0 = blockIdx.y*16, k0 = blockIdx.x*16;
  int tid = threadIdx.x, ty = tid >> 4, tx = tid & 15;
  __shared__ float Am[16*17], Ak[16*17];
  const float* Kc = Kzx + c*MZ*NX;
  float acc = 0;
  for (int nc = 0; nc < NX; nc += 16) {
    Am[ty*17+tx] = Kc[(m0+ty)*NX + nc + tx];
    Ak[ty*17+tx] = Kc[(k0+ty)*NX + nc + tx];
    __syncthreads();
    #pragma unroll
    for (int p = 0; p < 16; ++p) acc += Am[ty*17+p] * Ak[tx*17+p];
    __syncthreads();
  }
  int m = m0+ty, k = k0+tx, idx = c*MZ*MZ + m*MZ + k;
  float kzz = Kzz[idx];
  float dia = (m == k) ? 1.0f : 0.0f;
  Kzzj[idx] = kzz + dia*JIT;
  KzzB[idx] = kzz + acc*INV_S2 + dia*2.0f*JIT;
}

// ----------------------------------------------------------------------------
// FUSED Cholesky + ylam + triangular solve, float4-vectorized trailing updates.
// Layouts:
//   As  : 64KB col-major floats As[k*MZ + i] (unchanged).
//   Bres: 64KB float4 chunks. Bres[t*32 + (rc ^ (t&31))] = W^T-residual rows
//         4rc..4rc+3 of test-column t (XOR chunk swizzle spreads banks).
//   pan : pan[i] = (L[i][j],L[i][j+1],L[i][j+2],L[i][j+3]) for current panel.
// Per panel jb: waves 0-1 (tid<128) run the scalar chain (rsqrtf), write pan,
// update ylam residual bs, and SOLVE chunk jb of their column (1 b128 rmw).
// Then all 512 threads do rank-4 updates: As via (rg=tid&31 row-chunk,
// kp=tid>>5 col-partition) b128 rmw + pan[k] broadcast; Bres via (rg row-chunk
// if rg>jb, kp col-partition, 8 cols) b128 rmw + solved-chunk broadcast.
// 3 LDS instrs per 4 elements (was 3 per element) -> ~4x fewer LDS ops.
// Update guards imply only pan rows >= j+4 (valid) are ever consumed.
// ----------------------------------------------------------------------------
__global__ __launch_bounds__(512) void k_chol(const float* __restrict__ Kzzj, const float* __restrict__ KzzB,
    const float* __restrict__ LamU, const float* __restrict__ Kxz,
    float* __restrict__ ssq, float* __restrict__ fmean)
{
  int which = blockIdx.x & 1, c = blockIdx.x >> 1;
  const float* Ain = (which ? KzzB : Kzzj) + c*MZ*MZ;
  const float4* KxzC4 = (const float4*)(Kxz + (size_t)c*TN*MZ);
  __shared__ float  As[MZ*MZ];     // 64 KB
  __shared__ float4 Bres[MZ*32];   // 64 KB
  __shared__ float4 pan[MZ];
  __shared__ float  bs[MZ];
  int tid = threadIdx.x;
  {
    float4* d4 = (float4*)As; const float4* s4 = (const float4*)Ain;
    #pragma unroll
    for (int r = 0; r < 8; ++r) d4[tid + 512*r] = s4[tid + 512*r];
    #pragma unroll
    for (int r = 0; r < 8; ++r) {
      int f = tid + 512*r;
      int t = f >> 5, i4 = f & 31;
      Bres[t*32 + (i4 ^ (t & 31))] = KxzC4[f];   // coalesced read, spread write
    }
  }
  if (tid < MZ) bs[tid] = which ? LamU[c*MZ + tid] : 0.0f;
  __syncthreads();
  float sq = 0.0f, fm = 0.0f;
  int rg = tid & 31;    // row-chunk owner (rows 4rg..4rg+3)
  int kp = tid >> 5;    // column partition 0..15
  float4* As4 = (float4*)As;
  for (int jb = 0; jb < 32; ++jb) {
    int j = jb*4;
    if (tid < MZ) {
      int i = tid;
      float r0 = As[(j+0)*MZ + i], r1 = As[(j+1)*MZ + i], r2 = As[(j+2)*MZ + i], r3 = As[(j+3)*MZ + i];
      float a00 = As[j*MZ+j];
      float a10 = As[j*MZ+j+1], a20 = As[j*MZ+j+2], a30 = As[j*MZ+j+3];
      float a11 = As[(j+1)*MZ+j+1], a21 = As[(j+1)*MZ+j+2], a31 = As[(j+1)*MZ+j+3];
      float a22 = As[(j+2)*MZ+j+2], a32 = As[(j+2)*MZ+j+3];
      float a33 = As[(j+3)*MZ+j+3];
      float bj0 = bs[j], bj1 = bs[j+1], bj2 = bs[j+2], bj3 = bs[j+3];
      float id0 = rsqrtf(a00);
      float l10 = a10*id0, l20 = a20*id0, l30 = a30*id0;
      float id1 = rsqrtf(a11 - l10*l10);
      float l21 = (a21 - l20*l10)*id1, l31 = (a31 - l30*l10)*id1;
      float id2 = rsqrtf(a22 - l20*l20 - l21*l21);
      float l32 = (a32 - l30*l20 - l31*l21)*id2;
      float id3 = rsqrtf(a33 - l30*l30 - l31*l31 - l32*l32);
      float c0 = r0*id0;
      float c1 = (r1 - c0*l10)*id1;
      float c2 = (r2 - c0*l20 - c1*l21)*id2;
      float c3 = (r3 - c0*l30 - c1*l31 - c2*l32)*id3;
      float y0 = bj0*id0;
      float y1 = (bj1 - l10*y0)*id1;
      float y2 = (bj2 - l20*y0 - l21*y1)*id2;
      float y3 = (bj3 - l30*y0 - l31*y1 - l32*y2)*id3;
      pan[i] = make_float4(c0, c1, c2, c3);
      if (i >= j+4) bs[i] -= c0*y0 + c1*y1 + c2*y2 + c3*y3;
      // W-solve for column t = i (chunk jb), write solution back in place
      int wc = i*32 + (jb ^ (i & 31));
      float4 wch = Bres[wc];
      float w0 = wch.x*id0;
      float w1 = (wch.y - l10*w0)*id1;
      float w2 = (wch.z - l20*w0 - l21*w1)*id2;
      float w3 = (wch.w - l30*w0 - l31*w1 - l32*w2)*id3;
      Bres[wc] = make_float4(w0, w1, w2, w3);
      sq += w0*w0 + w1*w1 + w2*w2 + w3*w3;
      fm += w0*y0 + w1*y1 + w2*y2 + w3*y3;
    }
    __syncthreads();
    // own pan rows (only consumed under guards that imply rows >= j+4: valid)
    float4 p0 = pan[4*rg+0], p1 = pan[4*rg+1], p2 = pan[4*rg+2], p3 = pan[4*rg+3];
    // As trailing update: columns k ≡ kp (mod 16), k in [j+4, 4rg+3]
    {
      int kstart = (j + 4) + ((kp - (j + 4)) & 15);
      int kend = 4*rg + 3;
      for (int k = kstart; k <= kend; k += 16) {
        float4 ck = pan[k];
        float4 a4 = As4[k*32 + rg];
        a4.x -= p0.x*ck.x + p0.y*ck.y + p0.z*ck.z + p0.w*ck.w;
        a4.y -= p1.x*ck.x + p1.y*ck.y + p1.z*ck.z + p1.w*ck.w;
        a4.z -= p2.x*ck.x + p2.y*ck.y + p2.z*ck.z + p2.w*ck.w;
        a4.w -= p3.x*ck.x + p3.y*ck.y + p3.z*ck.z + p3.w*ck.w;
        As4[k*32 + rg] = a4;
      }
    }
    // Bres trailing update: row-chunk rg (rows >= j+4 iff rg > jb), cols ≡ kp mod 16
    if (rg > jb) {
      #pragma unroll
      for (int t8 = 0; t8 < 8; ++t8) {
        int t = kp + 16*t8;
        float4 wv = Bres[t*32 + (jb ^ (t & 31))];    // solved chunk (broadcastish)
        int bi = t*32 + (rg ^ (t & 31));
        float4 b4 = Bres[bi];
        b4.x -= p0.x*wv.x + p0.y*wv.y + p0.z*wv.z + p0.w*wv.w;
        b4.y -= p1.x*wv.x + p1.y*wv.y + p1.z*wv.z + p1.w*wv.w;
        b4.z -= p2.x*wv.x + p2.y*wv.y + p2.z*wv.z + p2.w*wv.w;
        b4.w -= p3.x*wv.x + p3.y*wv.y + p3.z*wv.z + p3.w*wv.w;
        Bres[bi] = b4;
      }
    }
    __syncthreads();
  }
  if (tid < MZ) {
    ssq[(which*CC + c)*TN + tid] = sq;
    if (which) fmean[c*TN + tid] = fm;
  }
}

// out[0][t][c] = f_mean ; out[1][t][c] = f_var.T = Kxx - sum(Am^2) + sum(Ab^2)
__global__ __launch_bounds__(256) void k_final(const float* __restrict__ fmean, const float* __restrict__ Kxxd,
    const float* __restrict__ ssq, float* __restrict__ out)
{
  int idx = blockIdx.x*256 + threadIdx.x;
  if (idx >= TN*CC) return;
  int t = idx / CC, c = idx % CC;
  out[idx] = fmean[c*TN + t];
  out[TN*CC + idx] = Kxxd[c*TN + t] - ssq[c*TN + t] + ssq[CC*TN + c*TN + t];
}

extern "C" void kernel_launch(void* const* d_in, const int* in_sizes, int n_in,
                              void* d_out, int out_size, void* d_ws, size_t ws_size,
                              hipStream_t stream) {
  (void)in_sizes; (void)n_in; (void)out_size; (void)ws_size;
  const float* X  = (const float*)d_in[0];
  const float* Y  = (const float*)d_in[1];
  const float* Z  = (const float*)d_in[2];
  const float* Xt = (const float*)d_in[3];
  const float* W1 = (const float*)d_in[4];
  const float* b1 = (const float*)d_in[5];
  const float* W2 = (const float*)d_in[6];
  const float* b2 = (const float*)d_in[7];
  const float* W3 = (const float*)d_in[8];
  float* ws  = (float*)d_ws;
  float* out = (float*)d_out;

  float* XS   = ws + OFF_XS;
  float* A1   = ws + OFF_A1;
  float* A2   = ws + OFF_A2;
  float* G1   = ws + OFF_G1;
  float* G2   = ws + OFF_G2;
  float* W2T  = ws + OFF_W2T;
  float* Base = ws + OFF_BASE;
  float* Kzx  = ws + OFF_KZX;
  float* Kzz  = ws + OFF_KZZ;
  float* Kxz  = ws + OFF_KXZ;
  float* Kxxd = ws + OFF_KXXD;
  float* Kzzj = ws + OFF_KZZJ;
  float* KzzB = ws + OFF_KZZB;
  float* LamU = ws + OFF_LAMU;
  float* ssq  = ws + OFF_SSQ;
  float* fmean= ws + OFF_FMEAN;

  k_w2t<<<128, 128, 0, stream>>>(W2, W2T, LamU);
  k_features<<<S_TOT, 128, 0, stream>>>(X, Z, Xt, W1, b1, W2, b2, W3, W2T, XS, A1, A2, G1, G2);
  k_base<<<dim3(16, 8, 3), 256, 0, stream>>>(XS, A1, A2, Base);
  k_gram<<<dim3(16, 8, 3*CC), 256, 0, stream>>>(G1, G2, Base, Y, Kzx, Kzz, Kxz, LamU);
  k_kxxd<<<TN, 128, 0, stream>>>(XS, A1, A2, G1, G2, Kxxd);
  k_kzzb<<<dim3(8, 8, CC), 256, 0, stream>>>(Kzx, Kzz, Kzzj, KzzB);
  k_chol<<<2*CC, 512, 0, stream>>>(Kzzj, KzzB, LamU, Kxz, ssq, fmean);
  k_final<<<(TN*CC + 255)/256, 256, 0, stream>>>(fmean, Kxxd, ssq, out);
}